// Round 1
// baseline (483.755 us; speedup 1.0000x reference)
//
#include <hip/hip_runtime.h>
#include <cstdio>
#include <cstdint>
#include <cstddef>

// Problem constants (B=4, S=2048, D=1024, F=2048, E=8, K=2, CF=1.25)
#define T_TOK 8192
#define E_N 8
#define D_M 1024
#define F_F 2048
#define A_N (T_TOK * 2)      // 16384 assignments
#define CAP 2560             // ceil(1.25 * 16384 / 8)
#define NCHUNK (A_N / 64)    // 256 chunks of 64 assignments

typedef __attribute__((ext_vector_type(4))) float floatx4;
typedef __attribute__((ext_vector_type(8))) short shortx8;

__device__ __forceinline__ unsigned short f2bf(float f) {
    union { float f; unsigned int u; } v; v.f = f;
    unsigned int u = v.u;
    u += 0x7fffu + ((u >> 16) & 1u);   // round-to-nearest-even
    return (unsigned short)(u >> 16);
}
__device__ __forceinline__ float bf2f(unsigned short h) {
    union { unsigned int u; float f; } v; v.u = ((unsigned int)h) << 16;
    return v.f;
}

// async global->LDS, 16B per lane (dest = wave-uniform base + lane*16)
__device__ __forceinline__ void async16(const unsigned short* g, unsigned short* l) {
    __builtin_amdgcn_global_load_lds(
        (const __attribute__((address_space(1))) unsigned int*)(g),
        (__attribute__((address_space(3))) unsigned int*)(l),
        16, 0, 0);
}

// ---------------- Router: one wave per token, top-2 experts + weights ----------------
__global__ void router_kernel(const float* __restrict__ x,
                              const float* __restrict__ rw,
                              const float* __restrict__ rb,
                              int* __restrict__ tk_e,
                              float* __restrict__ tk_w) {
    int t = blockIdx.x * 4 + (threadIdx.x >> 6);
    int lane = threadIdx.x & 63;
    float acc[E_N];
#pragma unroll
    for (int e = 0; e < E_N; ++e) acc[e] = 0.f;
    const float* xr = x + (size_t)t * D_M;
    for (int d = lane; d < D_M; d += 64) {
        float xv = xr[d];
        const float* r = rw + d * E_N;
#pragma unroll
        for (int e = 0; e < E_N; ++e) acc[e] += xv * r[e];
    }
#pragma unroll
    for (int off = 32; off > 0; off >>= 1) {
#pragma unroll
        for (int e = 0; e < E_N; ++e) acc[e] += __shfl_down(acc[e], off);
    }
    if (lane == 0) {
        float la[E_N];
#pragma unroll
        for (int e = 0; e < E_N; ++e) la[e] = acc[e] + rb[e];
        int e0 = 0; float l0 = la[0];
#pragma unroll
        for (int e = 1; e < E_N; ++e) { if (la[e] > l0) { l0 = la[e]; e0 = e; } }
        int e1 = -1; float l1 = -3.0e38f;
#pragma unroll
        for (int e = 0; e < E_N; ++e) { if (e != e0 && la[e] > l1) { l1 = la[e]; e1 = e; } }
        // top2 softmax renormalized == sigmoid of logit gap
        float w0 = 1.f / (1.f + expf(l1 - l0));
        tk_e[2 * t]     = e0;
        tk_e[2 * t + 1] = e1;
        tk_w[2 * t]     = w0;
        tk_w[2 * t + 1] = 1.f - w0;
    }
}

// ------ Per-chunk expert histogram + slot_token init (fused; grid 80x256 = 20480) ------
__global__ void hist_init_kernel(const int* __restrict__ tk_e, int* __restrict__ hist,
                                 int* __restrict__ slot_token) {
    int i = blockIdx.x * 256 + threadIdx.x;
    if (i < E_N * CAP) slot_token[i] = -1;
    if (i < A_N) {   // blocks 0..63 fully active, 64..79 uniformly skip
        int lane = threadIdx.x & 63;
        int chunk = i >> 6;
        int e = tk_e[i];
#pragma unroll
        for (int ee = 0; ee < E_N; ++ee) {
            unsigned long long b = __ballot(e == ee);
            if (lane == ee) hist[chunk * E_N + ee] = (int)__popcll(b);
        }
    }
}

// ------ Parallel exclusive prefix over 256 chunks, per expert: wave e scans expert e ------
__global__ void scan_kernel(const int* __restrict__ hist, int* __restrict__ cpre) {
    int e = threadIdx.x >> 6;    // 8 waves, one per expert
    int lane = threadIdx.x & 63; // lane handles chunks 4*lane .. 4*lane+3
    int h0 = hist[(4 * lane + 0) * E_N + e];
    int h1 = hist[(4 * lane + 1) * E_N + e];
    int h2 = hist[(4 * lane + 2) * E_N + e];
    int h3 = hist[(4 * lane + 3) * E_N + e];
    int t = h0 + h1 + h2 + h3;
    int inc = t;
#pragma unroll
    for (int off = 1; off < 64; off <<= 1) {
        int v = __shfl_up(inc, off);
        if (lane >= off) inc += v;
    }
    int base = inc - t;   // exclusive prefix of lane totals
    cpre[(4 * lane + 0) * E_N + e] = base;
    cpre[(4 * lane + 1) * E_N + e] = base + h0;
    cpre[(4 * lane + 2) * E_N + e] = base + h0 + h1;
    cpre[(4 * lane + 3) * E_N + e] = base + h0 + h1 + h2;
}

// ---------------- Rank within expert (stable order), capacity drop, slot maps ----------------
__global__ void slot_kernel(const int* __restrict__ tk_e, const int* __restrict__ cpre,
                            int* __restrict__ a_slot, int* __restrict__ slot_token) {
    int a = blockIdx.x * 256 + threadIdx.x;
    int lane = threadIdx.x & 63;
    int chunk = a >> 6;
    int e = tk_e[a];
    unsigned long long mymask = 0;
#pragma unroll
    for (int ee = 0; ee < E_N; ++ee) {
        unsigned long long b = __ballot(e == ee);
        if (e == ee) mymask = b;
    }
    int rank = cpre[chunk * E_N + e] + (int)__popcll(mymask & ((1ull << lane) - 1ull));
    int slot = (rank < CAP) ? e * CAP + rank : -1;
    a_slot[a] = slot;
    if (slot >= 0) slot_token[slot] = a >> 1;
}

// ------ Gather tokens into [E*CAP, D] bf16 buffer (zeros for empty slots); 16B/lane ------
__global__ void dispatch_kernel(const float* __restrict__ x, const int* __restrict__ slot_token,
                                unsigned short* __restrict__ xbuf) {
    int r = blockIdx.x * 2 + (threadIdx.x >> 7);
    int c = (threadIdx.x & 127) * 8;
    int tok = slot_token[r];
    float4 v0 = {0.f, 0.f, 0.f, 0.f}, v1 = {0.f, 0.f, 0.f, 0.f};
    if (tok >= 0) {
        const float* p = x + (size_t)tok * D_M + c;
        v0 = *(const float4*)p;
        v1 = *(const float4*)(p + 4);
    }
    union { unsigned short s[8]; uint4 u; } o;
    o.s[0] = f2bf(v0.x); o.s[1] = f2bf(v0.y); o.s[2] = f2bf(v0.z); o.s[3] = f2bf(v0.w);
    o.s[4] = f2bf(v1.x); o.s[5] = f2bf(v1.y); o.s[6] = f2bf(v1.z); o.s[7] = f2bf(v1.w);
    *(uint4*)(xbuf + (size_t)r * D_M + c) = o.u;
}

// ------ Weight convert+transpose for BOTH w1 and w2 in one launch ------
// w1: [e][D][F] f32 -> w1t [e][F][D] bf16 (R=D,C=F); w2: [e][F][D] -> w2t [e][D][F] (R=F,C=D)
__global__ void wconv2_kernel(const float* __restrict__ w1, const float* __restrict__ w2,
                              unsigned short* __restrict__ w1t, unsigned short* __restrict__ w2t) {
    __shared__ float tile[32][33];
    int id = blockIdx.x;
    bool second = id >= 16384;
    const float* in = second ? w2 : w1;
    unsigned short* outp = second ? w2t : w1t;
    int R = second ? F_F : D_M;
    int C = second ? D_M : F_F;
    int local = second ? id - 16384 : id;
    int e = local >> 11;            // 2048 blocks per expert either way
    int rem = local & 2047;
    int nrt = R >> 5;
    int rt = rem % nrt;
    int ct = rem / nrt;
    int r0 = rt * 32, c0 = ct * 32;
    const float* ine = in + (size_t)e * D_M * F_F;
    unsigned short* oute = outp + (size_t)e * D_M * F_F;
    int tr = threadIdx.x >> 3;
    int tc = (threadIdx.x & 7) * 4;
    float4 v = *(const float4*)(ine + (size_t)(r0 + tr) * C + c0 + tc);
    tile[tr][tc + 0] = v.x; tile[tr][tc + 1] = v.y;
    tile[tr][tc + 2] = v.z; tile[tr][tc + 3] = v.w;
    __syncthreads();
    int oc = threadIdx.x >> 3;          // local out-row (= in col)
    int orr = (threadIdx.x & 7) * 4;    // local out-col (= in row)
    union { unsigned short s[4]; uint2 u; } o;
#pragma unroll
    for (int j = 0; j < 4; ++j) o.s[j] = f2bf(tile[orr + j][oc]);
    *(uint2*)(oute + (size_t)(c0 + oc) * R + r0 + orr) = o.u;
}

// ---------------- bf16 MFMA GEMM v2: deep-pipelined counted-vmcnt schedule ----------------
// C[e] = epi(A[e][M,K] @ B[e][N,K]^T + bias[e])
// BM=256 x BN=128 tile, BK=32, 512 threads (8 waves, 2Mx4N), per-wave 128x32 output
// (acc[8][2] of 16x16x32 MFMA). LDS = 4-deep ring of (A 16KB + B 8KB) = 96KB.
// Schedule per K-tile t: s_waitcnt vmcnt(6) [never 0 in steady state: tiles t+1,t+2
// stay in flight ACROSS the barrier] -> raw s_barrier -> stage tile t+3 into the ring
// slot freed at the PREVIOUS barrier -> 10x ds_read_b128 -> setprio(1) 16 MFMA setprio(0).
// Race-freedom: buf[(t+3)&3] was last read at tile t-1; those reads complete before each
// wave reaches tile t's barrier (MFMA consumption drains lgkm); DMA issued after it.
// Landing of tile t guaranteed by the counted wait + barrier (vmcnt 3/0 for last 2 tiles).
// XOR swizzle (64B rows, 4 chunks of 16B): LDS slot (row r, chunk p) holds global chunk
// p ^ ((r>>1)&3), applied on the GLOBAL SOURCE side (DMA dest is HW-linear); frag
// ds_read XORs the same term -> 8 distinct 16B slots per 8 lanes, conflict-free.
// MFMA operands swapped (bf, af) -> D transposed: 8B packed C stores (same as verified v1).
template <int EPI>
__global__ __launch_bounds__(512, 2) void gemm2_kernel(
    const unsigned short* __restrict__ A,
    const unsigned short* __restrict__ B,
    const float* __restrict__ bias,
    unsigned short* __restrict__ C,
    int M, int N, int K, int ntn) {
    __shared__ __align__(16) unsigned short sh[4 * 12288];   // 4 x (A 8192 + B 4096) shorts
    int id = blockIdx.x;
    int e = id & 7;                  // expert == XCD (round-robin dispatch) for L2 affinity
    int local = id >> 3;
    int m0 = (local / ntn) * 256;
    int n0 = (local % ntn) * 128;
    const unsigned short* Ae = A + (size_t)e * M * K + (size_t)m0 * K;
    const unsigned short* Be = B + (size_t)e * N * K + (size_t)n0 * K;
    int tid = threadIdx.x;
    int lane = tid & 63;
    int w = tid >> 6;
    int l15 = lane & 15;
    int l4 = lane >> 4;
    int wm = (w >> 2) * 128;         // wave row block (0 / 128)
    int wn = (w & 3) * 32;           // wave col block (0/32/64/96)
    int S = ((l15 >> 1) & 3) ^ l4;   // swizzled k-chunk for fragment reads

    // staging source: thread t covers row (t>>2) [+128 for A load1], 16B chunk lc
    int lc = (tid & 3) ^ ((tid >> 3) & 3);
    const unsigned short* gA0 = Ae + (size_t)(tid >> 2) * K + lc * 8;
    const unsigned short* gA1 = gA0 + (size_t)128 * K;
    const unsigned short* gB0 = Be + (size_t)(tid >> 2) * K + lc * 8;

    // fragment LDS base offsets (shorts, within one ring slot)
    int aoff = (wm + l15) * 32 + S * 8;
    int boff = 8192 + (wn + l15) * 32 + S * 8;

    floatx4 acc[8][2];
#pragma unroll
    for (int i = 0; i < 8; ++i) {
        acc[i][0] = (floatx4){0.f, 0.f, 0.f, 0.f};
        acc[i][1] = (floatx4){0.f, 0.f, 0.f, 0.f};
    }

    int NT = K >> 5;
    auto STAGE = [&](int u) {
        int bs = (u & 3) * 12288;
        int kof = u * 32;
        async16(gA0 + kof, sh + bs + tid * 8);
        async16(gA1 + kof, sh + bs + 4096 + tid * 8);
        async16(gB0 + kof, sh + bs + 8192 + tid * 8);
    };
    // prologue: 3 tiles in flight before first wait
    STAGE(0); STAGE(1); STAGE(2);

    for (int t = 0; t < NT; ++t) {
        if (t < NT - 2)        asm volatile("s_waitcnt vmcnt(6)" ::: "memory");
        else if (t == NT - 2)  asm volatile("s_waitcnt vmcnt(3)" ::: "memory");
        else                   asm volatile("s_waitcnt vmcnt(0)" ::: "memory");
        __builtin_amdgcn_s_barrier();        // publish tile t's DMA to all waves
        __builtin_amdgcn_sched_barrier(0);   // nothing hoists above the barrier
        if (t + 3 < NT) STAGE(t + 3);        // into slot freed at previous barrier
        int bs = (t & 3) * 12288;
        const unsigned short* ap = sh + bs + aoff;
        const unsigned short* bp = sh + bs + boff;
        shortx8 af[8], bf[2];
#pragma unroll
        for (int j = 0; j < 2; ++j) bf[j] = *(const shortx8*)(bp + j * 512);
#pragma unroll
        for (int i = 0; i < 8; ++i) af[i] = *(const shortx8*)(ap + i * 512);
        __builtin_amdgcn_s_setprio(1);
#pragma unroll
        for (int i = 0; i < 8; ++i)
#pragma unroll
            for (int j = 0; j < 2; ++j)
                acc[i][j] = __builtin_amdgcn_mfma_f32_16x16x32_bf16(bf[j], af[i], acc[i][j], 0, 0, 0);
        __builtin_amdgcn_s_setprio(0);
    }

    // Epilogue: swapped-operand D layout: lane row m = lane&15, cols n = l4*4 + reg
#pragma unroll
    for (int i = 0; i < 8; ++i) {
        int row = m0 + wm + i * 16 + l15;
#pragma unroll
        for (int j = 0; j < 2; ++j) {
            int ncol = n0 + wn + j * 16 + l4 * 4;
            float4 bv = *(const float4*)(bias + (size_t)e * N + ncol);
            union { unsigned short s[4]; uint2 u; } o;
#pragma unroll
            for (int r = 0; r < 4; ++r) {
                float v = acc[i][j][r] + ((const float*)&bv)[r];
                if (EPI == 0) v = 0.5f * v * (1.0f + erff(v * 0.70710678118654752f));
                o.s[r] = f2bf(v);
            }
            *(uint2*)(C + ((size_t)e * M + row) * N + ncol) = o.u;
        }
    }
}

// ---------------- Combine: out[t] = sum_k w_k * eo[slot_k]; 16B reads, 32B writes ----------------
__global__ void combine_kernel(const unsigned short* __restrict__ eo,
                               const int* __restrict__ a_slot,
                               const float* __restrict__ tk_w,
                               float* __restrict__ out) {
    int t = blockIdx.x * 2 + (threadIdx.x >> 7);
    int c = (threadIdx.x & 127) * 8;
    int s0 = a_slot[2 * t], s1 = a_slot[2 * t + 1];
    float w0 = tk_w[2 * t], w1 = tk_w[2 * t + 1];
    float o[8];
#pragma unroll
    for (int k = 0; k < 8; ++k) o[k] = 0.f;
    if (s0 >= 0) {
        union { unsigned short s[8]; uint4 u; } v;
        v.u = *(const uint4*)(eo + (size_t)s0 * D_M + c);
#pragma unroll
        for (int k = 0; k < 8; ++k) o[k] += w0 * bf2f(v.s[k]);
    }
    if (s1 >= 0) {
        union { unsigned short s[8]; uint4 u; } v;
        v.u = *(const uint4*)(eo + (size_t)s1 * D_M + c);
#pragma unroll
        for (int k = 0; k < 8; ++k) o[k] += w1 * bf2f(v.s[k]);
    }
    float* po = out + (size_t)t * D_M + c;
    *(float4*)po = (float4){o[0], o[1], o[2], o[3]};
    *(float4*)(po + 4) = (float4){o[4], o[5], o[6], o[7]};
}

extern "C" void kernel_launch(void* const* d_in, const int* in_sizes, int n_in,
                              void* d_out, int out_size, void* d_ws, size_t ws_size,
                              hipStream_t stream) {
    const float* x  = (const float*)d_in[0];
    const float* rw = (const float*)d_in[1];
    const float* rb = (const float*)d_in[2];
    const float* w1 = (const float*)d_in[3];
    const float* b1 = (const float*)d_in[4];
    const float* w2 = (const float*)d_in[5];
    const float* b2 = (const float*)d_in[6];
    float* out = (float*)d_out;

    char* ws = (char*)d_ws;
    size_t off = 0;
    auto alloc = [&](size_t bytes) -> char* {
        char* p = ws + off;
        off += (bytes + 255) & ~(size_t)255;
        return p;
    };
    unsigned short* w1t  = (unsigned short*)alloc((size_t)E_N * D_M * F_F * 2);  // [E][F][D] bf16
    unsigned short* w2t  = (unsigned short*)alloc((size_t)E_N * D_M * F_F * 2);  // [E][D][F] bf16
    unsigned short* xbuf = (unsigned short*)alloc((size_t)E_N * CAP * D_M * 2);  // [E*CAP][D] bf16
    unsigned short* h    = (unsigned short*)alloc((size_t)E_N * CAP * F_F * 2);  // [E*CAP][F] bf16
    unsigned short* eo   = (unsigned short*)alloc((size_t)E_N * CAP * D_M * 2);  // [E*CAP][D] bf16
    int*   tk_e       = (int*)alloc((size_t)A_N * 4);
    float* tk_w       = (float*)alloc((size_t)A_N * 4);
    int*   hist       = (int*)alloc((size_t)NCHUNK * E_N * 4);
    int*   cpre       = (int*)alloc((size_t)NCHUNK * E_N * 4);
    int*   a_slot     = (int*)alloc((size_t)A_N * 4);
    int*   slot_token = (int*)alloc((size_t)E_N * CAP * 4);
    if (off > ws_size) {
        fprintf(stderr, "kernel_launch: workspace too small: need %zu, have %zu\n", off, ws_size);
        return;
    }

    // weight bf16 transpose-convert (independent of routing; single launch for w1+w2)
    wconv2_kernel<<<32768, 256, 0, stream>>>(w1, w2, w1t, w2t);
    // routing pipeline
    router_kernel<<<T_TOK / 4, 256, 0, stream>>>(x, rw, rb, tk_e, tk_w);
    hist_init_kernel<<<80, 256, 0, stream>>>(tk_e, hist, slot_token);
    scan_kernel<<<1, 512, 0, stream>>>(hist, cpre);
    slot_kernel<<<A_N / 256, 256, 0, stream>>>(tk_e, cpre, a_slot, slot_token);
    dispatch_kernel<<<E_N * CAP / 2, 256, 0, stream>>>(x, slot_token, xbuf);
    // expert FFN: BM=256 x BN=128 tiles; FFN1 grid 8*10*16=1280 (exactly 5 full
    // CU-rounds at 1 block/CU), FFN2 grid 8*10*8=640
    gemm2_kernel<0><<<E_N * (CAP / 256) * (F_F / 128), 512, 0, stream>>>(
        xbuf, w1t, b1, h, CAP, F_F, D_M, F_F / 128);
    gemm2_kernel<1><<<E_N * (CAP / 256) * (D_M / 128), 512, 0, stream>>>(
        h, w2t, b2, eo, CAP, D_M, F_F, D_M / 128);
    // weighted combine
    combine_kernel<<<T_TOK / 2, 256, 0, stream>>>(eo, a_slot, tk_w, out);
}

// Round 2
// 483.508 us; speedup vs baseline: 1.0005x; 1.0005x over previous
//
#include <hip/hip_runtime.h>
#include <cstdio>
#include <cstdint>
#include <cstddef>

// Problem constants (B=4, S=2048, D=1024, F=2048, E=8, K=2, CF=1.25)
#define T_TOK 8192
#define E_N 8
#define D_M 1024
#define F_F 2048
#define A_N (T_TOK * 2)      // 16384 assignments
#define CAP 2560             // ceil(1.25 * 16384 / 8)
#define NCHUNK (A_N / 64)    // 256 chunks of 64 assignments

typedef __attribute__((ext_vector_type(4))) float floatx4;
typedef __attribute__((ext_vector_type(8))) short shortx8;

__device__ __forceinline__ unsigned short f2bf(float f) {
    union { float f; unsigned int u; } v; v.f = f;
    unsigned int u = v.u;
    u += 0x7fffu + ((u >> 16) & 1u);   // round-to-nearest-even
    return (unsigned short)(u >> 16);
}
__device__ __forceinline__ float bf2f(unsigned short h) {
    union { unsigned int u; float f; } v; v.u = ((unsigned int)h) << 16;
    return v.f;
}

// async global->LDS, 16B per lane (dest = wave-uniform base + lane*16)
__device__ __forceinline__ void async16(const unsigned short* g, unsigned short* l) {
    __builtin_amdgcn_global_load_lds(
        (const __attribute__((address_space(1))) unsigned int*)(g),
        (__attribute__((address_space(3))) unsigned int*)(l),
        16, 0, 0);
}

// ---------------- Router: one wave per token, top-2 experts + weights ----------------
__global__ void router_kernel(const float* __restrict__ x,
                              const float* __restrict__ rw,
                              const float* __restrict__ rb,
                              int* __restrict__ tk_e,
                              float* __restrict__ tk_w) {
    int t = blockIdx.x * 4 + (threadIdx.x >> 6);
    int lane = threadIdx.x & 63;
    float acc[E_N];
#pragma unroll
    for (int e = 0; e < E_N; ++e) acc[e] = 0.f;
    const float* xr = x + (size_t)t * D_M;
    for (int d = lane; d < D_M; d += 64) {
        float xv = xr[d];
        const float* r = rw + d * E_N;
#pragma unroll
        for (int e = 0; e < E_N; ++e) acc[e] += xv * r[e];
    }
#pragma unroll
    for (int off = 32; off > 0; off >>= 1) {
#pragma unroll
        for (int e = 0; e < E_N; ++e) acc[e] += __shfl_down(acc[e], off);
    }
    if (lane == 0) {
        float la[E_N];
#pragma unroll
        for (int e = 0; e < E_N; ++e) la[e] = acc[e] + rb[e];
        int e0 = 0; float l0 = la[0];
#pragma unroll
        for (int e = 1; e < E_N; ++e) { if (la[e] > l0) { l0 = la[e]; e0 = e; } }
        int e1 = -1; float l1 = -3.0e38f;
#pragma unroll
        for (int e = 0; e < E_N; ++e) { if (e != e0 && la[e] > l1) { l1 = la[e]; e1 = e; } }
        // top2 softmax renormalized == sigmoid of logit gap
        float w0 = 1.f / (1.f + expf(l1 - l0));
        tk_e[2 * t]     = e0;
        tk_e[2 * t + 1] = e1;
        tk_w[2 * t]     = w0;
        tk_w[2 * t + 1] = 1.f - w0;
    }
}

// ------ Per-chunk expert histogram + slot_token init (fused; grid 80x256 = 20480) ------
__global__ void hist_init_kernel(const int* __restrict__ tk_e, int* __restrict__ hist,
                                 int* __restrict__ slot_token) {
    int i = blockIdx.x * 256 + threadIdx.x;
    if (i < E_N * CAP) slot_token[i] = -1;
    if (i < A_N) {   // blocks 0..63 fully active, 64..79 uniformly skip
        int lane = threadIdx.x & 63;
        int chunk = i >> 6;
        int e = tk_e[i];
#pragma unroll
        for (int ee = 0; ee < E_N; ++ee) {
            unsigned long long b = __ballot(e == ee);
            if (lane == ee) hist[chunk * E_N + ee] = (int)__popcll(b);
        }
    }
}

// ------ Parallel exclusive prefix over 256 chunks, per expert: wave e scans expert e ------
__global__ void scan_kernel(const int* __restrict__ hist, int* __restrict__ cpre) {
    int e = threadIdx.x >> 6;    // 8 waves, one per expert
    int lane = threadIdx.x & 63; // lane handles chunks 4*lane .. 4*lane+3
    int h0 = hist[(4 * lane + 0) * E_N + e];
    int h1 = hist[(4 * lane + 1) * E_N + e];
    int h2 = hist[(4 * lane + 2) * E_N + e];
    int h3 = hist[(4 * lane + 3) * E_N + e];
    int t = h0 + h1 + h2 + h3;
    int inc = t;
#pragma unroll
    for (int off = 1; off < 64; off <<= 1) {
        int v = __shfl_up(inc, off);
        if (lane >= off) inc += v;
    }
    int base = inc - t;   // exclusive prefix of lane totals
    cpre[(4 * lane + 0) * E_N + e] = base;
    cpre[(4 * lane + 1) * E_N + e] = base + h0;
    cpre[(4 * lane + 2) * E_N + e] = base + h0 + h1;
    cpre[(4 * lane + 3) * E_N + e] = base + h0 + h1 + h2;
}

// ---------------- Rank within expert (stable order), capacity drop, slot maps ----------------
__global__ void slot_kernel(const int* __restrict__ tk_e, const int* __restrict__ cpre,
                            int* __restrict__ a_slot, int* __restrict__ slot_token) {
    int a = blockIdx.x * 256 + threadIdx.x;
    int lane = threadIdx.x & 63;
    int chunk = a >> 6;
    int e = tk_e[a];
    unsigned long long mymask = 0;
#pragma unroll
    for (int ee = 0; ee < E_N; ++ee) {
        unsigned long long b = __ballot(e == ee);
        if (e == ee) mymask = b;
    }
    int rank = cpre[chunk * E_N + e] + (int)__popcll(mymask & ((1ull << lane) - 1ull));
    int slot = (rank < CAP) ? e * CAP + rank : -1;
    a_slot[a] = slot;
    if (slot >= 0) slot_token[slot] = a >> 1;
}

// ------ Gather tokens into [E*CAP, D] bf16 buffer (zeros for empty slots); 16B/lane ------
__global__ void dispatch_kernel(const float* __restrict__ x, const int* __restrict__ slot_token,
                                unsigned short* __restrict__ xbuf) {
    int r = blockIdx.x * 2 + (threadIdx.x >> 7);
    int c = (threadIdx.x & 127) * 8;
    int tok = slot_token[r];
    float4 v0 = {0.f, 0.f, 0.f, 0.f}, v1 = {0.f, 0.f, 0.f, 0.f};
    if (tok >= 0) {
        const float* p = x + (size_t)tok * D_M + c;
        v0 = *(const float4*)p;
        v1 = *(const float4*)(p + 4);
    }
    union { unsigned short s[8]; uint4 u; } o;
    o.s[0] = f2bf(v0.x); o.s[1] = f2bf(v0.y); o.s[2] = f2bf(v0.z); o.s[3] = f2bf(v0.w);
    o.s[4] = f2bf(v1.x); o.s[5] = f2bf(v1.y); o.s[6] = f2bf(v1.z); o.s[7] = f2bf(v1.w);
    *(uint4*)(xbuf + (size_t)r * D_M + c) = o.u;
}

// ------ Weight convert+transpose for BOTH w1 and w2 in one launch ------
// w1: [e][D][F] f32 -> w1t [e][F][D] bf16 (R=D,C=F); w2: [e][F][D] -> w2t [e][D][F] (R=F,C=D)
__global__ void wconv2_kernel(const float* __restrict__ w1, const float* __restrict__ w2,
                              unsigned short* __restrict__ w1t, unsigned short* __restrict__ w2t) {
    __shared__ float tile[32][33];
    int id = blockIdx.x;
    bool second = id >= 16384;
    const float* in = second ? w2 : w1;
    unsigned short* outp = second ? w2t : w1t;
    int R = second ? F_F : D_M;
    int C = second ? D_M : F_F;
    int local = second ? id - 16384 : id;
    int e = local >> 11;            // 2048 blocks per expert either way
    int rem = local & 2047;
    int nrt = R >> 5;
    int rt = rem % nrt;
    int ct = rem / nrt;
    int r0 = rt * 32, c0 = ct * 32;
    const float* ine = in + (size_t)e * D_M * F_F;
    unsigned short* oute = outp + (size_t)e * D_M * F_F;
    int tr = threadIdx.x >> 3;
    int tc = (threadIdx.x & 7) * 4;
    float4 v = *(const float4*)(ine + (size_t)(r0 + tr) * C + c0 + tc);
    tile[tr][tc + 0] = v.x; tile[tr][tc + 1] = v.y;
    tile[tr][tc + 2] = v.z; tile[tr][tc + 3] = v.w;
    __syncthreads();
    int oc = threadIdx.x >> 3;          // local out-row (= in col)
    int orr = (threadIdx.x & 7) * 4;    // local out-col (= in row)
    union { unsigned short s[4]; uint2 u; } o;
#pragma unroll
    for (int j = 0; j < 4; ++j) o.s[j] = f2bf(tile[orr + j][oc]);
    *(uint2*)(oute + (size_t)(c0 + oc) * R + r0 + orr) = o.u;
}

// ---------------- bf16 MFMA GEMM v3: 4-phase interleave + counted vmcnt (T2+T3+T4+T5) -----
// C[e] = epi(A[e][M,K] @ B[e][N,K]^T + bias[e])
// BM=256 x BN=128, BK=64, 512 threads (8 waves 4Mx2N), wave-tile 64x64 (acc 4x4 of
// 16x16x32) -> LDS bytes/FLOP = 1/32 (the v2 regression's 128x32 tile was 1/25.6).
// LDS: 3-slot ring x 48KB (A 32K + B 16K) = 144KB, 1 block/CU.
// Per K-tile t: 4 phases (p = ks*2+mh). Each phase: {ds_read 6 or 2 x b128 || issue 2
// staging DMAs for tile t+2} -> s_barrier -> lgkmcnt(0)+sched_barrier(0) (rule #18) ->
// setprio(1) 8 MFMA setprio(0) -> s_barrier. Tile boundary (once per tile): counted
// s_waitcnt vmcnt(6) -- tile t+2's 6 loads STAY IN FLIGHT across the barrier; vmcnt(0)
// only at the tail -> s_barrier publishes tile t+1's DMA.
// Ring safety: slot (t+2)%3 was last read at tile t-1; those ds_reads complete before
// tile t-1's MFMAs (lgkmcnt(0)) which precede the t-1 -> t boundary barrier.
// XOR swizzle (proven 0-conflict in v1): stage chunk = (tid&7)^(srow&7); frag read
// chunk = (ks*4+l4)^(l15&7) -> each consecutive-8-lane group hits 8 distinct 16B
// granules. MFMA operands swapped (bf, af): D rows = l15, cols = l4*4+reg; identical
// k-order to v1 -> bitwise-identical output.
template <int EPI>
__global__ __launch_bounds__(512, 2) void gemm3_kernel(
    const unsigned short* __restrict__ A,
    const unsigned short* __restrict__ B,
    const float* __restrict__ bias,
    unsigned short* __restrict__ C,
    int M, int N, int K, int ntn) {
    __shared__ __align__(16) unsigned short sh[3 * 24576];   // 144 KiB ring
    int id = blockIdx.x;
    int e = id & 7;                  // expert == XCD (round-robin dispatch): w[e] L2-resident
    int local = id >> 3;
    int m0 = (local / ntn) * 256;
    int n0 = (local % ntn) * 128;
    const unsigned short* Ae = A + (size_t)e * M * K + (size_t)m0 * K;
    const unsigned short* Be = B + (size_t)e * N * K + (size_t)n0 * K;
    int tid = threadIdx.x;
    int lane = tid & 63;
    int w = tid >> 6;
    int l15 = lane & 15;
    int l4 = lane >> 4;
    int wm = (w >> 1) * 64;          // 4 row-groups: 0/64/128/192
    int wn = (w & 1) * 64;           // 2 col-groups: 0/64
    int sx = l15 & 7;
    int sw0 = (l4 ^ sx) * 8;         // ks=0 swizzled chunk offset (shorts)
    int sw1 = ((4 + l4) ^ sx) * 8;   // ks=1

    // staging: thread covers row srow (+64p), 16B chunk (tid&7)^(srow&7)
    int srow = tid >> 3;             // 0..63
    int scol = ((tid & 7) ^ (srow & 7)) * 8;
    const unsigned short* gA0 = Ae + (size_t)(srow      ) * K + scol;
    const unsigned short* gA1 = Ae + (size_t)(srow +  64) * K + scol;
    const unsigned short* gA2 = Ae + (size_t)(srow + 128) * K + scol;
    const unsigned short* gA3 = Ae + (size_t)(srow + 192) * K + scol;
    const unsigned short* gB0 = Be + (size_t)(srow      ) * K + scol;
    const unsigned short* gB1 = Be + (size_t)(srow +  64) * K + scol;
    int dst = tid * 8;               // linear LDS dest (shorts)

    int abase = (wm + l15) * 64;             // A frag row base (shorts, within slot)
    int bbase = 16384 + (wn + l15) * 64;     // B region at 32KB

    floatx4 acc[4][4];
#pragma unroll
    for (int i = 0; i < 4; ++i)
#pragma unroll
        for (int j = 0; j < 4; ++j) acc[i][j] = (floatx4){0.f, 0.f, 0.f, 0.f};

    int NT = K >> 6;

    // prologue: tiles 0,1 -> slots 0,1 (12 loads in flight), land tile 0 (vmcnt 6)
    {
        async16(gA0,      sh +         dst);  async16(gA1,      sh +  4096 + dst);
        async16(gA2,      sh +  8192 + dst);  async16(gA3,      sh + 12288 + dst);
        async16(gB0,      sh + 16384 + dst);  async16(gB1,      sh + 20480 + dst);
        async16(gA0 + 64, sh + 24576 + dst);  async16(gA1 + 64, sh + 28672 + dst);
        async16(gA2 + 64, sh + 32768 + dst);  async16(gA3 + 64, sh + 36864 + dst);
        async16(gB0 + 64, sh + 40960 + dst);  async16(gB1 + 64, sh + 45056 + dst);
    }
    asm volatile("s_waitcnt vmcnt(6)" ::: "memory");
    __builtin_amdgcn_s_barrier();
    __builtin_amdgcn_sched_barrier(0);

    int bs = 0, ss = 49152, kstage = 128;
    for (int t = 0; t < NT; ++t) {
        const unsigned short* sA = sh + bs + abase;
        const unsigned short* sB = sh + bs + bbase;
        bool do_stage = (kstage < K);
        shortx8 bf[4];
#pragma unroll
        for (int p = 0; p < 4; ++p) {
            const int ks = p >> 1;
            const int mh = p & 1;
            int swz = (ks == 0) ? sw0 : sw1;
            if (mh == 0) {
#pragma unroll
                for (int j = 0; j < 4; ++j)
                    bf[j] = *(const shortx8*)(sB + j * 1024 + swz);
            }
            shortx8 a0 = *(const shortx8*)(sA + (mh * 2 + 0) * 1024 + swz);
            shortx8 a1 = *(const shortx8*)(sA + (mh * 2 + 1) * 1024 + swz);
            if (do_stage) {   // 2 staging DMAs per phase (6 total for tile t+2)
                if (p == 0) { async16(gA0 + kstage, sh + ss +         dst);
                              async16(gA1 + kstage, sh + ss +  4096 + dst); }
                if (p == 1) { async16(gA2 + kstage, sh + ss +  8192 + dst);
                              async16(gA3 + kstage, sh + ss + 12288 + dst); }
                if (p == 2) { async16(gB0 + kstage, sh + ss + 16384 + dst);
                              async16(gB1 + kstage, sh + ss + 20480 + dst); }
            }
            __builtin_amdgcn_s_barrier();
            asm volatile("s_waitcnt lgkmcnt(0)" ::: "memory");
            __builtin_amdgcn_sched_barrier(0);
            __builtin_amdgcn_s_setprio(1);
#pragma unroll
            for (int j = 0; j < 4; ++j)
                acc[mh * 2 + 0][j] = __builtin_amdgcn_mfma_f32_16x16x32_bf16(bf[j], a0, acc[mh * 2 + 0][j], 0, 0, 0);
#pragma unroll
            for (int j = 0; j < 4; ++j)
                acc[mh * 2 + 1][j] = __builtin_amdgcn_mfma_f32_16x16x32_bf16(bf[j], a1, acc[mh * 2 + 1][j], 0, 0, 0);
            __builtin_amdgcn_s_setprio(0);
            if (p < 3) __builtin_amdgcn_s_barrier();
        }
        if (t < NT - 1) {   // tile boundary: next tile landed + published; NEVER drain mid-loop
            if (t < NT - 2) asm volatile("s_waitcnt vmcnt(6)" ::: "memory");
            else            asm volatile("s_waitcnt vmcnt(0)" ::: "memory");
            __builtin_amdgcn_s_barrier();
            __builtin_amdgcn_sched_barrier(0);
        }
        bs += 24576; if (bs == 73728) bs = 0;
        ss += 24576; if (ss == 73728) ss = 0;
        kstage += 64;
    }

    // Epilogue: swapped-operand D layout: lane row m = lane&15, cols n = l4*4 + reg
#pragma unroll
    for (int i = 0; i < 4; ++i) {
        int row = m0 + wm + i * 16 + l15;
#pragma unroll
        for (int j = 0; j < 4; ++j) {
            int ncol = n0 + wn + j * 16 + l4 * 4;
            float4 bv = *(const float4*)(bias + (size_t)e * N + ncol);
            union { unsigned short s[4]; uint2 u; } o;
#pragma unroll
            for (int r = 0; r < 4; ++r) {
                float v = acc[i][j][r] + ((const float*)&bv)[r];
                if (EPI == 0) v = 0.5f * v * (1.0f + erff(v * 0.70710678118654752f));
                o.s[r] = f2bf(v);
            }
            *(uint2*)(C + ((size_t)e * M + row) * N + ncol) = o.u;
        }
    }
}

// ---------------- Combine: out[t] = sum_k w_k * eo[slot_k]; 16B reads, 32B writes ----------------
__global__ void combine_kernel(const unsigned short* __restrict__ eo,
                               const int* __restrict__ a_slot,
                               const float* __restrict__ tk_w,
                               float* __restrict__ out) {
    int t = blockIdx.x * 2 + (threadIdx.x >> 7);
    int c = (threadIdx.x & 127) * 8;
    int s0 = a_slot[2 * t], s1 = a_slot[2 * t + 1];
    float w0 = tk_w[2 * t], w1 = tk_w[2 * t + 1];
    float o[8];
#pragma unroll
    for (int k = 0; k < 8; ++k) o[k] = 0.f;
    if (s0 >= 0) {
        union { unsigned short s[8]; uint4 u; } v;
        v.u = *(const uint4*)(eo + (size_t)s0 * D_M + c);
#pragma unroll
        for (int k = 0; k < 8; ++k) o[k] += w0 * bf2f(v.s[k]);
    }
    if (s1 >= 0) {
        union { unsigned short s[8]; uint4 u; } v;
        v.u = *(const uint4*)(eo + (size_t)s1 * D_M + c);
#pragma unroll
        for (int k = 0; k < 8; ++k) o[k] += w1 * bf2f(v.s[k]);
    }
    float* po = out + (size_t)t * D_M + c;
    *(float4*)po = (float4){o[0], o[1], o[2], o[3]};
    *(float4*)(po + 4) = (float4){o[4], o[5], o[6], o[7]};
}

extern "C" void kernel_launch(void* const* d_in, const int* in_sizes, int n_in,
                              void* d_out, int out_size, void* d_ws, size_t ws_size,
                              hipStream_t stream) {
    const float* x  = (const float*)d_in[0];
    const float* rw = (const float*)d_in[1];
    const float* rb = (const float*)d_in[2];
    const float* w1 = (const float*)d_in[3];
    const float* b1 = (const float*)d_in[4];
    const float* w2 = (const float*)d_in[5];
    const float* b2 = (const float*)d_in[6];
    float* out = (float*)d_out;

    char* ws = (char*)d_ws;
    size_t off = 0;
    auto alloc = [&](size_t bytes) -> char* {
        char* p = ws + off;
        off += (bytes + 255) & ~(size_t)255;
        return p;
    };
    unsigned short* w1t  = (unsigned short*)alloc((size_t)E_N * D_M * F_F * 2);  // [E][F][D] bf16
    unsigned short* w2t  = (unsigned short*)alloc((size_t)E_N * D_M * F_F * 2);  // [E][D][F] bf16
    unsigned short* xbuf = (unsigned short*)alloc((size_t)E_N * CAP * D_M * 2);  // [E*CAP][D] bf16
    unsigned short* h    = (unsigned short*)alloc((size_t)E_N * CAP * F_F * 2);  // [E*CAP][F] bf16
    unsigned short* eo   = (unsigned short*)alloc((size_t)E_N * CAP * D_M * 2);  // [E*CAP][D] bf16
    int*   tk_e       = (int*)alloc((size_t)A_N * 4);
    float* tk_w       = (float*)alloc((size_t)A_N * 4);
    int*   hist       = (int*)alloc((size_t)NCHUNK * E_N * 4);
    int*   cpre       = (int*)alloc((size_t)NCHUNK * E_N * 4);
    int*   a_slot     = (int*)alloc((size_t)A_N * 4);
    int*   slot_token = (int*)alloc((size_t)E_N * CAP * 4);
    if (off > ws_size) {
        fprintf(stderr, "kernel_launch: workspace too small: need %zu, have %zu\n", off, ws_size);
        return;
    }

    // weight bf16 transpose-convert (independent of routing; single launch for w1+w2)
    wconv2_kernel<<<32768, 256, 0, stream>>>(w1, w2, w1t, w2t);
    // routing pipeline
    router_kernel<<<T_TOK / 4, 256, 0, stream>>>(x, rw, rb, tk_e, tk_w);
    hist_init_kernel<<<80, 256, 0, stream>>>(tk_e, hist, slot_token);
    scan_kernel<<<1, 512, 0, stream>>>(hist, cpre);
    slot_kernel<<<A_N / 256, 256, 0, stream>>>(tk_e, cpre, a_slot, slot_token);
    dispatch_kernel<<<E_N * CAP / 2, 256, 0, stream>>>(x, slot_token, xbuf);
    // expert FFN: BM=256 x BN=128. FFN1: 8*10*16 = 1280 blocks (exactly 5 rounds at
    // 1 block/CU, no tail); FFN2: 8*10*8 = 640 blocks
    gemm3_kernel<0><<<E_N * (CAP / 256) * (F_F / 128), 512, 0, stream>>>(
        xbuf, w1t, b1, h, CAP, F_F, D_M, F_F / 128);
    gemm3_kernel<1><<<E_N * (CAP / 256) * (D_M / 128), 512, 0, stream>>>(
        h, w2t, b2, eo, CAP, D_M, F_F, D_M / 128);
    // weighted combine
    combine_kernel<<<T_TOK / 2, 256, 0, stream>>>(eo, a_slot, tk_w, out);
}

// Round 3
// 440.283 us; speedup vs baseline: 1.0987x; 1.0982x over previous
//
#include <hip/hip_runtime.h>
#include <cstdio>
#include <cstdint>
#include <cstddef>

// Problem constants (B=4, S=2048, D=1024, F=2048, E=8, K=2, CF=1.25)
#define T_TOK 8192
#define E_N 8
#define D_M 1024
#define F_F 2048
#define A_N (T_TOK * 2)      // 16384 assignments
#define CAP 2560             // ceil(1.25 * 16384 / 8)
#define NCHUNK (A_N / 64)    // 256 chunks of 64 assignments

typedef __attribute__((ext_vector_type(4))) float floatx4;
typedef __attribute__((ext_vector_type(8))) short shortx8;

__device__ __forceinline__ unsigned short f2bf(float f) {
    union { float f; unsigned int u; } v; v.f = f;
    unsigned int u = v.u;
    u += 0x7fffu + ((u >> 16) & 1u);   // round-to-nearest-even
    return (unsigned short)(u >> 16);
}
__device__ __forceinline__ float bf2f(unsigned short h) {
    union { unsigned int u; float f; } v; v.u = ((unsigned int)h) << 16;
    return v.f;
}

// async global->LDS, 16B per lane (dest = wave-uniform base + lane*16)
__device__ __forceinline__ void async16(const unsigned short* g, unsigned short* l) {
    __builtin_amdgcn_global_load_lds(
        (const __attribute__((address_space(1))) unsigned int*)(g),
        (__attribute__((address_space(3))) unsigned int*)(l),
        16, 0, 0);
}

// ---------------- Router: one wave per token, top-2 experts + weights ----------------
__global__ void router_kernel(const float* __restrict__ x,
                              const float* __restrict__ rw,
                              const float* __restrict__ rb,
                              int* __restrict__ tk_e,
                              float* __restrict__ tk_w) {
    int t = blockIdx.x * 4 + (threadIdx.x >> 6);
    int lane = threadIdx.x & 63;
    float acc[E_N];
#pragma unroll
    for (int e = 0; e < E_N; ++e) acc[e] = 0.f;
    const float* xr = x + (size_t)t * D_M;
    for (int d = lane; d < D_M; d += 64) {
        float xv = xr[d];
        const float* r = rw + d * E_N;
#pragma unroll
        for (int e = 0; e < E_N; ++e) acc[e] += xv * r[e];
    }
#pragma unroll
    for (int off = 32; off > 0; off >>= 1) {
#pragma unroll
        for (int e = 0; e < E_N; ++e) acc[e] += __shfl_down(acc[e], off);
    }
    if (lane == 0) {
        float la[E_N];
#pragma unroll
        for (int e = 0; e < E_N; ++e) la[e] = acc[e] + rb[e];
        int e0 = 0; float l0 = la[0];
#pragma unroll
        for (int e = 1; e < E_N; ++e) { if (la[e] > l0) { l0 = la[e]; e0 = e; } }
        int e1 = -1; float l1 = -3.0e38f;
#pragma unroll
        for (int e = 0; e < E_N; ++e) { if (e != e0 && la[e] > l1) { l1 = la[e]; e1 = e; } }
        // top2 softmax renormalized == sigmoid of logit gap
        float w0 = 1.f / (1.f + expf(l1 - l0));
        tk_e[2 * t]     = e0;
        tk_e[2 * t + 1] = e1;
        tk_w[2 * t]     = w0;
        tk_w[2 * t + 1] = 1.f - w0;
    }
}

// ------ Per-chunk expert histogram + slot_token init (fused; grid 80x256 = 20480) ------
__global__ void hist_init_kernel(const int* __restrict__ tk_e, int* __restrict__ hist,
                                 int* __restrict__ slot_token) {
    int i = blockIdx.x * 256 + threadIdx.x;
    if (i < E_N * CAP) slot_token[i] = -1;
    if (i < A_N) {   // blocks 0..63 fully active, 64..79 uniformly skip
        int lane = threadIdx.x & 63;
        int chunk = i >> 6;
        int e = tk_e[i];
#pragma unroll
        for (int ee = 0; ee < E_N; ++ee) {
            unsigned long long b = __ballot(e == ee);
            if (lane == ee) hist[chunk * E_N + ee] = (int)__popcll(b);
        }
    }
}

// ------ Parallel exclusive prefix over 256 chunks, per expert: wave e scans expert e ------
__global__ void scan_kernel(const int* __restrict__ hist, int* __restrict__ cpre) {
    int e = threadIdx.x >> 6;    // 8 waves, one per expert
    int lane = threadIdx.x & 63; // lane handles chunks 4*lane .. 4*lane+3
    int h0 = hist[(4 * lane + 0) * E_N + e];
    int h1 = hist[(4 * lane + 1) * E_N + e];
    int h2 = hist[(4 * lane + 2) * E_N + e];
    int h3 = hist[(4 * lane + 3) * E_N + e];
    int t = h0 + h1 + h2 + h3;
    int inc = t;
#pragma unroll
    for (int off = 1; off < 64; off <<= 1) {
        int v = __shfl_up(inc, off);
        if (lane >= off) inc += v;
    }
    int base = inc - t;   // exclusive prefix of lane totals
    cpre[(4 * lane + 0) * E_N + e] = base;
    cpre[(4 * lane + 1) * E_N + e] = base + h0;
    cpre[(4 * lane + 2) * E_N + e] = base + h0 + h1;
    cpre[(4 * lane + 3) * E_N + e] = base + h0 + h1 + h2;
}

// ---------------- Rank within expert (stable order), capacity drop, slot maps ----------------
__global__ void slot_kernel(const int* __restrict__ tk_e, const int* __restrict__ cpre,
                            int* __restrict__ a_slot, int* __restrict__ slot_token) {
    int a = blockIdx.x * 256 + threadIdx.x;
    int lane = threadIdx.x & 63;
    int chunk = a >> 6;
    int e = tk_e[a];
    unsigned long long mymask = 0;
#pragma unroll
    for (int ee = 0; ee < E_N; ++ee) {
        unsigned long long b = __ballot(e == ee);
        if (e == ee) mymask = b;
    }
    int rank = cpre[chunk * E_N + e] + (int)__popcll(mymask & ((1ull << lane) - 1ull));
    int slot = (rank < CAP) ? e * CAP + rank : -1;
    a_slot[a] = slot;
    if (slot >= 0) slot_token[slot] = a >> 1;
}

// ------ Gather tokens into [E*CAP, D] bf16 buffer (zeros for empty slots); 16B/lane ------
__global__ void dispatch_kernel(const float* __restrict__ x, const int* __restrict__ slot_token,
                                unsigned short* __restrict__ xbuf) {
    int r = blockIdx.x * 2 + (threadIdx.x >> 7);
    int c = (threadIdx.x & 127) * 8;
    int tok = slot_token[r];
    float4 v0 = {0.f, 0.f, 0.f, 0.f}, v1 = {0.f, 0.f, 0.f, 0.f};
    if (tok >= 0) {
        const float* p = x + (size_t)tok * D_M + c;
        v0 = *(const float4*)p;
        v1 = *(const float4*)(p + 4);
    }
    union { unsigned short s[8]; uint4 u; } o;
    o.s[0] = f2bf(v0.x); o.s[1] = f2bf(v0.y); o.s[2] = f2bf(v0.z); o.s[3] = f2bf(v0.w);
    o.s[4] = f2bf(v1.x); o.s[5] = f2bf(v1.y); o.s[6] = f2bf(v1.z); o.s[7] = f2bf(v1.w);
    *(uint4*)(xbuf + (size_t)r * D_M + c) = o.u;
}

// ------ Weight convert+transpose v2: 64x64 tiles, 128B-contiguous transposed stores ------
// w1: [e][D][F] f32 -> w1t [e][F][D] bf16 (R=D,C=F); w2: [e][F][D] -> w2t [e][D][F] (R=F,C=D)
// Old version: 32x32 tiles, 32768 blocks, 8B stores at 64B granule (half-efficient writes).
// New: 8192 blocks of 256 threads. Load: 4 threads/row x 64B f32 (256B/row contiguous).
// Convert to bf16 in registers, stage in LDS [64][72] (144B rows: 16B-aligned for b128
// writes; write pattern granule-balanced). Store: out-row j handled by 4 threads x 32B
// -> 128B contiguous per output row.
__global__ void wconv64_kernel(const float* __restrict__ w1, const float* __restrict__ w2,
                               unsigned short* __restrict__ w1t, unsigned short* __restrict__ w2t) {
    __shared__ __align__(16) unsigned short tile[64][72];
    int id = blockIdx.x;
    bool second = id >= 4096;
    const float* in = second ? w2 : w1;
    unsigned short* outp = second ? w2t : w1t;
    int R = second ? F_F : D_M;
    int C = second ? D_M : F_F;
    int local = second ? id - 4096 : id;
    int e = local >> 9;            // 512 blocks per expert-matrix
    int rem = local & 511;
    int nrt = R >> 6;
    int rt = rem % nrt;
    int ct = rem / nrt;
    int r0 = rt * 64, c0 = ct * 64;
    const float* ine = in + (size_t)e * D_M * F_F + (size_t)r0 * C + c0;
    unsigned short* oute = outp + (size_t)e * D_M * F_F + (size_t)c0 * R + r0;

    // load 64 floats.. per thread: row lr, 16 consecutive floats (64B)
    int lr = threadIdx.x >> 2;
    int lc = (threadIdx.x & 3) * 16;
    const float* p = ine + (size_t)lr * C + lc;
    float4 v0 = *(const float4*)(p + 0);
    float4 v1 = *(const float4*)(p + 4);
    float4 v2 = *(const float4*)(p + 8);
    float4 v3 = *(const float4*)(p + 12);
    union { unsigned short s[8]; uint4 u; } a, b;
    a.s[0] = f2bf(v0.x); a.s[1] = f2bf(v0.y); a.s[2] = f2bf(v0.z); a.s[3] = f2bf(v0.w);
    a.s[4] = f2bf(v1.x); a.s[5] = f2bf(v1.y); a.s[6] = f2bf(v1.z); a.s[7] = f2bf(v1.w);
    b.s[0] = f2bf(v2.x); b.s[1] = f2bf(v2.y); b.s[2] = f2bf(v2.z); b.s[3] = f2bf(v2.w);
    b.s[4] = f2bf(v3.x); b.s[5] = f2bf(v3.y); b.s[6] = f2bf(v3.z); b.s[7] = f2bf(v3.w);
    *(uint4*)&tile[lr][lc] = a.u;
    *(uint4*)&tile[lr][lc + 8] = b.u;
    __syncthreads();

    // store: out-row j (= in col j), thread covers 16 out-cols (= in rows) = 32B
    int j = threadIdx.x >> 2;
    int q = threadIdx.x & 3;
    union { unsigned short s[16]; uint4 u[2]; } o;
#pragma unroll
    for (int k = 0; k < 16; ++k) o.s[k] = tile[q * 16 + k][j];
    unsigned short* po = oute + (size_t)j * R + q * 16;
    *(uint4*)po = o.u[0];
    *(uint4*)(po + 8) = o.u[1];
}

// ---------------- bf16 MFMA GEMM (register-prefetch pipeline + XOR-swizzled LDS) ----------
// C[e] = epi(A[e][M,K] @ B[e][N,K]^T + bias[e])
// 128x128 tile, BK=64, 4 waves (2x2), each wave 64x64 via 4x4 of 16x16x32 MFMA.
// Pipeline per K-iter: B1(drain DMA) -> ds_read ALL frags to regs -> B2(reads done)
// -> issue next tile's DMA -> MFMA on regs (overlaps DMA in flight).
// XOR swizzle on the GLOBAL SOURCE side (LDS dest order is HW-fixed): LDS slot
// (row r, chunk k) holds global chunk k^(r&7) -> frag ds_read_b128 conflict-free.
// MFMA operands swapped (bf,af) -> D transposed: 8B packed C stores.
template <int EPI>
__global__ __launch_bounds__(256, 3) void gemm_kernel(
    const unsigned short* __restrict__ A,
    const unsigned short* __restrict__ B,
    const float* __restrict__ bias,
    unsigned short* __restrict__ C,
    int M, int N, int K, int nt) {
    __shared__ __align__(16) unsigned short As[128 * 64];
    __shared__ __align__(16) unsigned short Bs[128 * 64];
    int id = blockIdx.x;
    int e = id & 7;
    int local = id >> 3;
    int m0 = (local / nt) * 128;
    int n0 = (local % nt) * 128;
    const unsigned short* Ae = A + (size_t)e * M * K + (size_t)m0 * K;
    const unsigned short* Be = B + (size_t)e * N * K + (size_t)n0 * K;
    int tid = threadIdx.x;
    int lane = tid & 63;
    int wave = tid >> 6;
    int wm = (wave >> 1) * 64;
    int wn = (wave & 1) * 64;
    int l15 = lane & 15;
    int l4 = lane >> 4;
    int srow = tid >> 3;                         // staging row 0..31 (per 32-row group)
    int kg = (tid & 7) ^ (srow & 7);             // swizzled global chunk
    int scol = kg * 8;                           // global column offset (elements)
    int sx = l15 & 7;                            // fragment-read xor term (m&7)

    floatx4 acc[4][4];
#pragma unroll
    for (int i = 0; i < 4; ++i)
#pragma unroll
        for (int j = 0; j < 4; ++j) acc[i][j] = (floatx4){0.f, 0.f, 0.f, 0.f};

    // prologue: stage tile 0
#pragma unroll
    for (int p = 0; p < 4; ++p) {
        async16(Ae + (size_t)(p * 32 + srow) * K + scol, As + p * 2048 + tid * 8);
        async16(Be + (size_t)(p * 32 + srow) * K + scol, Bs + p * 2048 + tid * 8);
    }

    for (int kt = 0; kt < K; kt += 64) {
        __syncthreads();   // drains vmcnt(0): this tile's DMA visible
        shortx8 af[2][4], bf[2][4];
#pragma unroll
        for (int ks = 0; ks < 2; ++ks) {
            int kcx = ((ks * 4 + l4) ^ sx) * 8;
#pragma unroll
            for (int i = 0; i < 4; ++i) {
                af[ks][i] = *(const shortx8*)(As + (wm + i * 16 + l15) * 64 + kcx);
                bf[ks][i] = *(const shortx8*)(Bs + (wn + i * 16 + l15) * 64 + kcx);
            }
        }
        __syncthreads();   // all waves finished reading LDS (lgkm drained)
        if (kt + 64 < K) { // issue next tile's DMA; MFMA below overlaps it
#pragma unroll
            for (int p = 0; p < 4; ++p) {
                async16(Ae + (size_t)(p * 32 + srow) * K + kt + 64 + scol, As + p * 2048 + tid * 8);
                async16(Be + (size_t)(p * 32 + srow) * K + kt + 64 + scol, Bs + p * 2048 + tid * 8);
            }
        }
#pragma unroll
        for (int ks = 0; ks < 2; ++ks)
#pragma unroll
            for (int i = 0; i < 4; ++i)
#pragma unroll
                for (int j = 0; j < 4; ++j)
                    acc[i][j] = __builtin_amdgcn_mfma_f32_16x16x32_bf16(bf[ks][j], af[ks][i], acc[i][j], 0, 0, 0);
    }

    // Epilogue: swapped-operand D layout: lane row m = lane&15, cols n = l4*4 + reg
#pragma unroll
    for (int i = 0; i < 4; ++i) {
        int row = m0 + wm + i * 16 + l15;
#pragma unroll
        for (int j = 0; j < 4; ++j) {
            int ncol = n0 + wn + j * 16 + l4 * 4;
            float4 bv = *(const float4*)(bias + (size_t)e * N + ncol);
            union { unsigned short s[4]; uint2 u; } o;
#pragma unroll
            for (int r = 0; r < 4; ++r) {
                float v = acc[i][j][r] + ((const float*)&bv)[r];
                if (EPI == 0) v = 0.5f * v * (1.0f + erff(v * 0.70710678118654752f));
                o.s[r] = f2bf(v);
            }
            *(uint2*)(C + ((size_t)e * M + row) * N + ncol) = o.u;
        }
    }
}

// ---------------- Combine: out[t] = sum_k w_k * eo[slot_k]; 16B reads, 32B writes ----------------
__global__ void combine_kernel(const unsigned short* __restrict__ eo,
                               const int* __restrict__ a_slot,
                               const float* __restrict__ tk_w,
                               float* __restrict__ out) {
    int t = blockIdx.x * 2 + (threadIdx.x >> 7);
    int c = (threadIdx.x & 127) * 8;
    int s0 = a_slot[2 * t], s1 = a_slot[2 * t + 1];
    float w0 = tk_w[2 * t], w1 = tk_w[2 * t + 1];
    float o[8];
#pragma unroll
    for (int k = 0; k < 8; ++k) o[k] = 0.f;
    if (s0 >= 0) {
        union { unsigned short s[8]; uint4 u; } v;
        v.u = *(const uint4*)(eo + (size_t)s0 * D_M + c);
#pragma unroll
        for (int k = 0; k < 8; ++k) o[k] += w0 * bf2f(v.s[k]);
    }
    if (s1 >= 0) {
        union { unsigned short s[8]; uint4 u; } v;
        v.u = *(const uint4*)(eo + (size_t)s1 * D_M + c);
#pragma unroll
        for (int k = 0; k < 8; ++k) o[k] += w1 * bf2f(v.s[k]);
    }
    float* po = out + (size_t)t * D_M + c;
    *(float4*)po = (float4){o[0], o[1], o[2], o[3]};
    *(float4*)(po + 4) = (float4){o[4], o[5], o[6], o[7]};
}

extern "C" void kernel_launch(void* const* d_in, const int* in_sizes, int n_in,
                              void* d_out, int out_size, void* d_ws, size_t ws_size,
                              hipStream_t stream) {
    const float* x  = (const float*)d_in[0];
    const float* rw = (const float*)d_in[1];
    const float* rb = (const float*)d_in[2];
    const float* w1 = (const float*)d_in[3];
    const float* b1 = (const float*)d_in[4];
    const float* w2 = (const float*)d_in[5];
    const float* b2 = (const float*)d_in[6];
    float* out = (float*)d_out;

    char* ws = (char*)d_ws;
    size_t off = 0;
    auto alloc = [&](size_t bytes) -> char* {
        char* p = ws + off;
        off += (bytes + 255) & ~(size_t)255;
        return p;
    };
    unsigned short* w1t  = (unsigned short*)alloc((size_t)E_N * D_M * F_F * 2);  // [E][F][D] bf16
    unsigned short* w2t  = (unsigned short*)alloc((size_t)E_N * D_M * F_F * 2);  // [E][D][F] bf16
    unsigned short* xbuf = (unsigned short*)alloc((size_t)E_N * CAP * D_M * 2);  // [E*CAP][D] bf16
    unsigned short* h    = (unsigned short*)alloc((size_t)E_N * CAP * F_F * 2);  // [E*CAP][F] bf16
    unsigned short* eo   = (unsigned short*)alloc((size_t)E_N * CAP * D_M * 2);  // [E*CAP][D] bf16
    int*   tk_e       = (int*)alloc((size_t)A_N * 4);
    float* tk_w       = (float*)alloc((size_t)A_N * 4);
    int*   hist       = (int*)alloc((size_t)NCHUNK * E_N * 4);
    int*   cpre       = (int*)alloc((size_t)NCHUNK * E_N * 4);
    int*   a_slot     = (int*)alloc((size_t)A_N * 4);
    int*   slot_token = (int*)alloc((size_t)E_N * CAP * 4);
    if (off > ws_size) {
        fprintf(stderr, "kernel_launch: workspace too small: need %zu, have %zu\n", off, ws_size);
        return;
    }

    // weight bf16 transpose-convert (independent of routing; single launch for w1+w2)
    wconv64_kernel<<<8192, 256, 0, stream>>>(w1, w2, w1t, w2t);
    // routing pipeline
    router_kernel<<<T_TOK / 4, 256, 0, stream>>>(x, rw, rb, tk_e, tk_w);
    hist_init_kernel<<<80, 256, 0, stream>>>(tk_e, hist, slot_token);
    scan_kernel<<<1, 512, 0, stream>>>(hist, cpre);
    slot_kernel<<<A_N / 256, 256, 0, stream>>>(tk_e, cpre, a_slot, slot_token);
    dispatch_kernel<<<E_N * CAP / 2, 256, 0, stream>>>(x, slot_token, xbuf);
    // expert FFN (1D grids: E * mt * nt blocks, XCD swizzle inside)
    gemm_kernel<0><<<E_N * (CAP / 128) * (F_F / 128), 256, 0, stream>>>(
        xbuf, w1t, b1, h, CAP, F_F, D_M, F_F / 128);
    gemm_kernel<1><<<E_N * (CAP / 128) * (D_M / 128), 256, 0, stream>>>(
        h, w2t, b2, eo, CAP, D_M, F_F, D_M / 128);
    // weighted combine
    combine_kernel<<<T_TOK / 2, 256, 0, stream>>>(eo, a_slot, tk_w, out);
}